// Round 4
// baseline (180.489 us; speedup 1.0000x reference)
//
#include <hip/hip_runtime.h>
#include <math.h>

#define BB 8
#define NN 4096
#define MM 4000
#define KK 5
#define NWAVE 16
#define QPB 64
#define CH 256                      // candidates per wave-chunk
#define GRP 8                       // candidates per s_load group
#define NG (CH / GRP)               // 32 groups
#define NPAD 4096
#define KNN_BLOCKS ((NN / QPB) * BB)   // 512

#define ACC_ROT    0
#define ACC_TRANS  1
#define ACC_ALIGN  2
#define ACC_DISP   3
#define ACC_DEFORM 4
#define ACC_LAP    5
#define ACC_RMSE   6   // 8 entries
#define ACC_COUNT  14

#define INFF __int_as_float(0x7F800000)

__device__ __forceinline__ float waveReduceSum(float v) {
#pragma unroll
    for (int off = 32; off > 0; off >>= 1) v += __shfl_down(v, off, 64);
    return v;
}

// One candidate: 3 fma (score, shifted by -|q|^2) + optional 2-op index pack
// + optional self-mask + 9-op sorted min/max insertion. Branchless.
template<bool SELF, bool PACK>
__device__ __forceinline__ void proc1(float4 c, int midx, int q,
                                      float ca, float cbq, float cc,
                                      float& b0, float& b1, float& b2,
                                      float& b3, float& b4) {
    float sc = fmaf(c.x, ca, fmaf(c.y, cbq, fmaf(c.z, cc, c.w)));
    float v;
    if (PACK) {
        unsigned pk = (__float_as_uint(sc) & 0xFFFFF000u) | (unsigned)midx;
        v = __uint_as_float(pk);
        if (SELF) v = (midx == q) ? INFF : v;
    } else {
        v = sc;
    }
    float t;
    b4 = fminf(b4, v);
    t = b3; b3 = fminf(t, b4); b4 = fmaxf(t, b4);
    t = b2; b2 = fminf(t, b3); b3 = fmaxf(t, b3);
    t = b1; b1 = fminf(t, b2); b2 = fmaxf(t, b2);
    t = b0; b0 = fminf(t, b1); b1 = fmaxf(t, b1);
}

// Scan a 256-candidate wave-uniform chunk. Candidates load via s_load
// (readfirstlane forces scalar); A/B ping-pong keeps the next group's
// s_loads in flight under the current group's VALU work.
template<bool SELF, bool PACK>
__device__ __forceinline__ void scanCH(const float4* __restrict__ cb, int tc,
                                       float ca, float cbq, float cc, int q,
                                       float& b0, float& b1, float& b2,
                                       float& b3, float& b4) {
    float4 A[GRP], B[GRP];
    int baseA = __builtin_amdgcn_readfirstlane(tc);
#pragma unroll
    for (int j = 0; j < GRP; ++j) A[j] = cb[baseA + j];

    for (int g = 0; g < NG; g += 2) {
        int baseB = __builtin_amdgcn_readfirstlane(tc + (g + 1) * GRP);
#pragma unroll
        for (int j = 0; j < GRP; ++j) B[j] = cb[baseB + j];
#pragma unroll
        for (int j = 0; j < GRP; ++j)
            proc1<SELF, PACK>(A[j], baseA + j, q, ca, cbq, cc, b0, b1, b2, b3, b4);

        int baseA2 = __builtin_amdgcn_readfirstlane(tc + (g + 2) * GRP);
        if (g + 2 < NG) {
#pragma unroll
            for (int j = 0; j < GRP; ++j) A[j] = cb[baseA2 + j];
        }
#pragma unroll
        for (int j = 0; j < GRP; ++j)
            proc1<SELF, PACK>(B[j], baseB + j, q, ca, cbq, cc, b0, b1, b2, b3, b4);
        baseA = baseA2;
    }
}

// K1: Y_rigid (padded float4 + norm), X padded float4 + norm, rmse/disp partials,
// rot/trans losses.
__global__ void k_prep(const float* __restrict__ Y, const float* __restrict__ X,
                       const float* __restrict__ Rp, const float* __restrict__ tp,
                       const float* __restrict__ Rg, const float* __restrict__ tg,
                       const float* __restrict__ dl,
                       float4* __restrict__ YrP, float4* __restrict__ XP,
                       float* __restrict__ acc) {
    int b = blockIdx.x >> 4;
    int n = ((blockIdx.x & 15) << 8) + threadIdx.x;
    size_t base = ((size_t)b * NN + n) * 3;
    float yx = Y[base + 0], yy = Y[base + 1], yz = Y[base + 2];

    float rp[9], rg[9], tpv[3], tgv[3];
#pragma unroll
    for (int i = 0; i < 9; ++i) { rp[i] = Rp[b * 9 + i]; rg[i] = Rg[b * 9 + i]; }
#pragma unroll
    for (int i = 0; i < 3; ++i) { tpv[i] = tp[b * 3 + i]; tgv[i] = tg[b * 3 + i]; }

    float p[3], dr2 = 0.f;
#pragma unroll
    for (int k = 0; k < 3; ++k) {
        float pv = fmaf(yx, rp[k * 3 + 0], fmaf(yy, rp[k * 3 + 1], fmaf(yz, rp[k * 3 + 2], tpv[k])));
        float gv = fmaf(yx, rg[k * 3 + 0], fmaf(yy, rg[k * 3 + 1], fmaf(yz, rg[k * 3 + 2], tgv[k])));
        p[k] = pv;
        float dd = pv - gv;
        dr2 = fmaf(dd, dd, dr2);
    }
    YrP[(size_t)b * NPAD + n] =
        make_float4(p[0], p[1], p[2], fmaf(p[0], p[0], fmaf(p[1], p[1], p[2] * p[2])));

    float4 xe;
    if (n < MM) {
        size_t xb = ((size_t)b * MM + n) * 3;
        float x0 = X[xb + 0], x1 = X[xb + 1], x2 = X[xb + 2];
        xe = make_float4(x0, x1, x2, fmaf(x0, x0, fmaf(x1, x1, x2 * x2)));
    } else {
        xe = make_float4(0.f, 0.f, 0.f, INFF);
    }
    XP[(size_t)b * NPAD + n] = xe;

    float d0 = dl[base + 0], d1 = dl[base + 1], d2 = dl[base + 2];
    float dsq = d0 * d0 + d1 * d1 + d2 * d2;

    dr2 = waveReduceSum(dr2);
    dsq = waveReduceSum(dsq);
    if ((threadIdx.x & 63) == 0) {
        atomicAdd(&acc[ACC_RMSE + b], dr2);
        atomicAdd(&acc[ACC_DISP], dsq);
    }

    if (threadIdx.x == 0 && (blockIdx.x & 15) == 0) {
        float tr = 0.f;
#pragma unroll
        for (int i = 0; i < 9; ++i) tr += rp[i] * rg[i];
        float c = (tr - 1.f) * 0.5f;
        c = fminf(fmaxf(c, -1.f + 1e-7f), 1.f - 1e-7f);
        float dx = tpv[0] - tgv[0], dy = tpv[1] - tgv[1], dz = tpv[2] - tgv[2];
        atomicAdd(&acc[ACC_ROT], acosf(c));
        atomicAdd(&acc[ACC_TRANS], sqrtf(dx * dx + dy * dy + dz * dz));
    }
}

// K2: L_align — 16 waves × 256-candidate chunks of padded X, 16-way LDS merge.
__global__ __launch_bounds__(1024, 8) void k_align(const float* __restrict__ Xh,
                                                   const float4* __restrict__ XP,
                                                   float* __restrict__ acc) {
    __shared__ float md[NWAVE][QPB][6];
    int tid = threadIdx.x, wave = tid >> 6, lane = tid & 63;
    int b = blockIdx.y;
    int q = blockIdx.x * QPB + lane;
    size_t qb = ((size_t)b * NN + q) * 3;
    float qx = Xh[qb + 0], qy = Xh[qb + 1], qz = Xh[qb + 2];
    float qn = fmaf(qx, qx, fmaf(qy, qy, qz * qz));
    const float4* cb = XP + (size_t)b * NPAD;

    float b0 = INFF, b1 = INFF, b2 = INFF, b3 = INFF, b4 = INFF;
    scanCH<false, false>(cb, wave * CH, -2.f * qx, -2.f * qy, -2.f * qz, 0,
                         b0, b1, b2, b3, b4);

    md[wave][lane][0] = b0; md[wave][lane][1] = b1; md[wave][lane][2] = b2;
    md[wave][lane][3] = b3; md[wave][lane][4] = b4; md[wave][lane][5] = INFF;
    __syncthreads();

    if (tid < QPB) {
        int l = tid;
        int pp[NWAVE];
#pragma unroll
        for (int w = 0; w < NWAVE; ++w) pp[w] = 0;
        float s = 0.f;
#pragma unroll
        for (int k = 0; k < KK; ++k) {
            float best = INFF; int bw = 0;
#pragma unroll
            for (int w = 0; w < NWAVE; ++w) {
                float d = md[w][l][pp[w]];
                if (d < best) { best = d; bw = w; }
            }
            s += fmaxf(best + qn, 0.f);   // undo -|q|^2 shift, clamp like reference
#pragma unroll
            for (int w = 0; w < NWAVE; ++w) pp[w] += (bw == w);
        }
        s = waveReduceSum(s);
        if (l == 0) atomicAdd(&acc[ACC_ALIGN], s);
    }
}

__device__ void finalize(const float* acc, float* out) {
    float a[ACC_COUNT];
#pragma unroll
    for (int i = 0; i < ACC_COUNT; ++i)
        a[i] = __hip_atomic_load(&acc[i], __ATOMIC_RELAXED, __HIP_MEMORY_SCOPE_AGENT);
    float L_rot = a[ACC_ROT] / BB;
    float L_trans = a[ACC_TRANS] / BB;
    float L_rmse = 0.f;
#pragma unroll
    for (int b = 0; b < BB; ++b) L_rmse += sqrtf(a[ACC_RMSE + b] / NN);
    L_rmse /= BB;
    float L_align = a[ACC_ALIGN] / ((float)BB * NN * KK);
    float L_disp = a[ACC_DISP] / ((float)BB * NN);
    float L_def = a[ACC_DEFORM] / ((float)BB * NN * KK);
    float L_lap = a[ACC_LAP] / ((float)BB * NN);
    float rigid = L_rot + L_trans + L_rmse;
    float nr = L_align + 0.01f * L_disp + 0.1f * L_def + 0.1f * L_lap;
    out[0] = rigid + nr; out[1] = rigid; out[2] = nr;
    out[3] = L_rot; out[4] = L_trans; out[5] = L_rmse;
    out[6] = L_align; out[7] = L_disp; out[8] = L_def; out[9] = L_lap;
}

// K3: kNN graph on Y_rigid (self-excluded), deform/lap epilogue, last-block finalize.
__global__ __launch_bounds__(1024, 8) void k_knn(const float4* __restrict__ YrP,
                                                 const float* __restrict__ Xh,
                                                 const float* __restrict__ dl,
                                                 float* __restrict__ acc,
                                                 unsigned* __restrict__ doneCnt,
                                                 float* __restrict__ out) {
    __shared__ float md[NWAVE][QPB][6];
    int tid = threadIdx.x, wave = tid >> 6, lane = tid & 63;
    int b = blockIdx.y;
    int q = blockIdx.x * QPB + lane;
    const float4* cb = YrP + (size_t)b * NPAD;
    float4 qp = cb[q];

    float b0 = INFF, b1 = INFF, b2 = INFF, b3 = INFF, b4 = INFF;
    // block's 64 queries lie entirely inside chunk (blockIdx.x >> 2)
    bool hasSelf = (wave == (blockIdx.x >> 2));
    if (hasSelf)
        scanCH<true, true>(cb, wave * CH, -2.f * qp.x, -2.f * qp.y, -2.f * qp.z, q,
                           b0, b1, b2, b3, b4);
    else
        scanCH<false, true>(cb, wave * CH, -2.f * qp.x, -2.f * qp.y, -2.f * qp.z, q,
                            b0, b1, b2, b3, b4);

    md[wave][lane][0] = b0; md[wave][lane][1] = b1; md[wave][lane][2] = b2;
    md[wave][lane][3] = b3; md[wave][lane][4] = b4; md[wave][lane][5] = INFF;
    __syncthreads();

    if (tid < QPB) {
        int l = tid;
        int pp[NWAVE];
#pragma unroll
        for (int w = 0; w < NWAVE; ++w) pp[w] = 0;
        int si[KK];
#pragma unroll
        for (int k = 0; k < KK; ++k) {
            float best = INFF; int bw = 0;
#pragma unroll
            for (int w = 0; w < NWAVE; ++w) {
                float d = md[w][l][pp[w]];
                if (d < best) { best = d; bw = w; }
            }
            si[k] = (int)(__float_as_uint(best) & 0xFFFu);
#pragma unroll
            for (int w = 0; w < NWAVE; ++w) pp[w] += (bw == w);
        }

        const float* xh = Xh + (size_t)b * NN * 3;
        const float* dlb = dl + (size_t)b * NN * 3;
        float xnx = xh[q * 3 + 0], xny = xh[q * 3 + 1], xnz = xh[q * 3 + 2];
        float dnx = dlb[q * 3 + 0], dny = dlb[q * 3 + 1], dnz = dlb[q * 3 + 2];

        float def = 0.f, sx = 0.f, sy = 0.f, sz = 0.f;
#pragma unroll
        for (int k = 0; k < KK; ++k) {
            int j = si[k];
            float4 yj = cb[j];
            float ex = (xh[j * 3 + 0] - xnx) - (yj.x - qp.x);
            float ey = (xh[j * 3 + 1] - xny) - (yj.y - qp.y);
            float ez = (xh[j * 3 + 2] - xnz) - (yj.z - qp.z);
            def += ex * ex + ey * ey + ez * ez;
            sx += dlb[j * 3 + 0]; sy += dlb[j * 3 + 1]; sz += dlb[j * 3 + 2];
        }
        float lx = dnx - sx / 5.f, ly = dny - sy / 5.f, lz = dnz - sz / 5.f;
        float lap = lx * lx + ly * ly + lz * lz;

        def = waveReduceSum(def);
        lap = waveReduceSum(lap);
        if (l == 0) {
            atomicAdd(&acc[ACC_DEFORM], def);
            atomicAdd(&acc[ACC_LAP], lap);
            __threadfence();
            unsigned t = __hip_atomic_fetch_add(doneCnt, 1u, __ATOMIC_ACQ_REL,
                                                __HIP_MEMORY_SCOPE_AGENT);
            if (t == KNN_BLOCKS - 1) finalize(acc, out);
        }
    }
}

extern "C" void kernel_launch(void* const* d_in, const int* in_sizes, int n_in,
                              void* d_out, int out_size, void* d_ws, size_t ws_size,
                              hipStream_t stream) {
    const float* Y  = (const float*)d_in[0];
    const float* X  = (const float*)d_in[1];
    const float* Rp = (const float*)d_in[2];
    const float* tp = (const float*)d_in[3];
    const float* Rg = (const float*)d_in[4];
    const float* tg = (const float*)d_in[5];
    const float* Xh = (const float*)d_in[6];
    const float* dl = (const float*)d_in[7];
    float* out = (float*)d_out;

    float*    acc     = (float*)d_ws;                          // 14 floats
    unsigned* doneCnt = (unsigned*)((char*)d_ws + 64);
    float4*   YrP     = (float4*)((char*)d_ws + 512);          // B*4096 float4
    float4*   XP      = YrP + (size_t)BB * NPAD;               // B*4096 float4

    hipMemsetAsync(d_ws, 0, 512, stream);
    hipLaunchKernelGGL(k_prep, dim3(BB * NN / 256), dim3(256), 0, stream,
                       Y, X, Rp, tp, Rg, tg, dl, YrP, XP, acc);
    hipLaunchKernelGGL(k_align, dim3(NN / QPB, BB), dim3(1024), 0, stream, Xh, XP, acc);
    hipLaunchKernelGGL(k_knn, dim3(NN / QPB, BB), dim3(1024), 0, stream,
                       YrP, Xh, dl, acc, doneCnt, out);
}

// Round 5
// 152.015 us; speedup vs baseline: 1.1873x; 1.1873x over previous
//
#include <hip/hip_runtime.h>
#include <math.h>

#define BB 8
#define NN 4096
#define MM 4000
#define KK 5
#define NWAVE 8
#define QPB 64
#define CH 256                       // candidates per wave-chunk (2 halves x 8 waves x 256)
#define NPAD 4096
#define MQ_BLK 256
#define M_KNN_BLOCKS (BB * NN / MQ_BLK)   // 128

#define ACC_ROT    0
#define ACC_TRANS  1
#define ACC_ALIGN  2
#define ACC_DISP   3
#define ACC_DEFORM 4
#define ACC_LAP    5
#define ACC_RMSE   6   // 8 entries
#define ACC_COUNT  14

#define INFF __int_as_float(0x7F800000)

__device__ __forceinline__ float waveReduceSum(float v) {
#pragma unroll
    for (int off = 32; off > 0; off >>= 1) v += __shfl_down(v, off, 64);
    return v;
}

// One candidate: 3 fma (score shifted by -|q|^2) + optional index pack (low 12
// mantissa bits) + optional self-mask + 9-op sorted min/max insert. Branchless.
template<bool SELF, bool PACK>
__device__ __forceinline__ void proc1(float4 c, int midx, int q,
                                      float ca, float cbq, float cc,
                                      float& b0, float& b1, float& b2,
                                      float& b3, float& b4) {
    float sc = fmaf(c.x, ca, fmaf(c.y, cbq, fmaf(c.z, cc, c.w)));
    float v;
    if (PACK) {
        unsigned pk = (__float_as_uint(sc) & 0xFFFFF000u) | (unsigned)midx;
        v = __uint_as_float(pk);
        if (SELF) v = (midx == q) ? INFF : v;
    } else {
        v = sc;
    }
    float t;
    b4 = fminf(b4, v);
    t = b3; b3 = fminf(t, b4); b4 = fmaxf(t, b4);
    t = b2; b2 = fminf(t, b3); b3 = fmaxf(t, b3);
    t = b1; b1 = fminf(t, b2); b2 = fmaxf(t, b2);
    t = b0; b0 = fminf(t, b1); b1 = fmaxf(t, b1);
}

// Scan a CH-candidate wave-uniform chunk starting at global index tc.
// readfirstlane forces scalar (s_load) candidate fetch. Round-3-proven body.
template<bool SELF, bool PACK>
__device__ __forceinline__ void scanCH(const float4* __restrict__ cb, int tc,
                                       float ca, float cbq, float cc, int q,
                                       float& b0, float& b1, float& b2,
                                       float& b3, float& b4) {
    for (int t0 = 0; t0 < CH; t0 += 8) {
        int base = __builtin_amdgcn_readfirstlane(tc + t0);
#pragma unroll
        for (int j = 0; j < 8; ++j) {
            float4 c = cb[base + j];
            proc1<SELF, PACK>(c, base + j, q, ca, cbq, cc, b0, b1, b2, b3, b4);
        }
    }
}

// K1: Y_rigid (padded float4 + norm), X padded float4 + norm, rmse/disp
// partials, rot/trans losses.
__global__ void k_prep(const float* __restrict__ Y, const float* __restrict__ X,
                       const float* __restrict__ Rp, const float* __restrict__ tp,
                       const float* __restrict__ Rg, const float* __restrict__ tg,
                       const float* __restrict__ dl,
                       float4* __restrict__ YrP, float4* __restrict__ XP,
                       float* __restrict__ acc) {
    int b = blockIdx.x >> 4;
    int n = ((blockIdx.x & 15) << 8) + threadIdx.x;
    size_t base = ((size_t)b * NN + n) * 3;
    float yx = Y[base + 0], yy = Y[base + 1], yz = Y[base + 2];

    float rp[9], rg[9], tpv[3], tgv[3];
#pragma unroll
    for (int i = 0; i < 9; ++i) { rp[i] = Rp[b * 9 + i]; rg[i] = Rg[b * 9 + i]; }
#pragma unroll
    for (int i = 0; i < 3; ++i) { tpv[i] = tp[b * 3 + i]; tgv[i] = tg[b * 3 + i]; }

    float p[3], dr2 = 0.f;
#pragma unroll
    for (int k = 0; k < 3; ++k) {
        float pv = fmaf(yx, rp[k * 3 + 0], fmaf(yy, rp[k * 3 + 1], fmaf(yz, rp[k * 3 + 2], tpv[k])));
        float gv = fmaf(yx, rg[k * 3 + 0], fmaf(yy, rg[k * 3 + 1], fmaf(yz, rg[k * 3 + 2], tgv[k])));
        p[k] = pv;
        float dd = pv - gv;
        dr2 = fmaf(dd, dd, dr2);
    }
    YrP[(size_t)b * NPAD + n] =
        make_float4(p[0], p[1], p[2], fmaf(p[0], p[0], fmaf(p[1], p[1], p[2] * p[2])));

    float4 xe;
    if (n < MM) {
        size_t xb = ((size_t)b * MM + n) * 3;
        float x0 = X[xb + 0], x1 = X[xb + 1], x2 = X[xb + 2];
        xe = make_float4(x0, x1, x2, fmaf(x0, x0, fmaf(x1, x1, x2 * x2)));
    } else {
        xe = make_float4(0.f, 0.f, 0.f, INFF);
    }
    XP[(size_t)b * NPAD + n] = xe;

    float d0 = dl[base + 0], d1 = dl[base + 1], d2 = dl[base + 2];
    float dsq = d0 * d0 + d1 * d1 + d2 * d2;

    dr2 = waveReduceSum(dr2);
    dsq = waveReduceSum(dsq);
    if ((threadIdx.x & 63) == 0) {
        atomicAdd(&acc[ACC_RMSE + b], dr2);
        atomicAdd(&acc[ACC_DISP], dsq);
    }

    if (threadIdx.x == 0 && (blockIdx.x & 15) == 0) {
        float tr = 0.f;
#pragma unroll
        for (int i = 0; i < 9; ++i) tr += rp[i] * rg[i];
        float c = (tr - 1.f) * 0.5f;
        c = fminf(fmaxf(c, -1.f + 1e-7f), 1.f - 1e-7f);
        float dx = tpv[0] - tgv[0], dy = tpv[1] - tgv[1], dz = tpv[2] - tgv[2];
        atomicAdd(&acc[ACC_ROT], acosf(c));
        atomicAdd(&acc[ACC_TRANS], sqrtf(dx * dx + dy * dy + dz * dz));
    }
}

#define MERGE_STEP(W) { float d = md[W][l][pp##W]; if (d < best) { best = d; bw = W; } }
#define MERGE_ADV()  { pp0 += (bw == 0); pp1 += (bw == 1); pp2 += (bw == 2); pp3 += (bw == 3); \
                       pp4 += (bw == 4); pp5 += (bw == 5); pp6 += (bw == 6); pp7 += (bw == 7); }

// K2a: L_align scan — 8 waves x 256-candidate chunks of one half of padded X;
// 8-way LDS merge; sorted-5 partial (+INF sentinel) to global scratch.
__global__ __launch_bounds__(512, 8) void k_align_scan(const float* __restrict__ Xh,
                                                       const float4* __restrict__ XP,
                                                       float* __restrict__ pa) {
    __shared__ float md[NWAVE][QPB][6];
    int tid = threadIdx.x, wave = tid >> 6, lane = tid & 63;
    int b = blockIdx.y, qg = blockIdx.x, half = blockIdx.z;
    int q = qg * QPB + lane;
    size_t qb = ((size_t)b * NN + q) * 3;
    float qx = Xh[qb + 0], qy = Xh[qb + 1], qz = Xh[qb + 2];
    const float4* cb = XP + (size_t)b * NPAD;

    float b0 = INFF, b1 = INFF, b2 = INFF, b3 = INFF, b4 = INFF;
    scanCH<false, false>(cb, half * 2048 + wave * CH, -2.f * qx, -2.f * qy, -2.f * qz, 0,
                         b0, b1, b2, b3, b4);

    md[wave][lane][0] = b0; md[wave][lane][1] = b1; md[wave][lane][2] = b2;
    md[wave][lane][3] = b3; md[wave][lane][4] = b4; md[wave][lane][5] = INFF;
    __syncthreads();

    if (tid < QPB) {
        int l = tid;
        int pp0 = 0, pp1 = 0, pp2 = 0, pp3 = 0, pp4 = 0, pp5 = 0, pp6 = 0, pp7 = 0;
        int qq = qg * QPB + l;
        float* dst = pa + (((size_t)b * NN + qq) * 2 + half) * 6;
#pragma unroll
        for (int k = 0; k < KK; ++k) {
            float best = INFF; int bw = 0;
            MERGE_STEP(0) MERGE_STEP(1) MERGE_STEP(2) MERGE_STEP(3)
            MERGE_STEP(4) MERGE_STEP(5) MERGE_STEP(6) MERGE_STEP(7)
            dst[k] = best;
            MERGE_ADV()
        }
        dst[5] = INFF;
    }
}

// K2b: merge the two sorted align partials, add |q|^2 back, clamp, reduce.
__global__ void m_align(const float* __restrict__ Xh, const float* __restrict__ pa,
                        float* __restrict__ acc) {
    int gid = blockIdx.x * MQ_BLK + threadIdx.x;       // 0 .. B*N-1
    size_t qb = (size_t)gid * 3;
    float qx = Xh[qb + 0], qy = Xh[qb + 1], qz = Xh[qb + 2];
    float qn = fmaf(qx, qx, fmaf(qy, qy, qz * qz));

    const float* p0 = pa + (size_t)gid * 12;
    const float* p1 = p0 + 6;
    int i = 0, j = 0;
    float s = 0.f;
#pragma unroll
    for (int k = 0; k < KK; ++k) {
        float a = p0[i], c = p1[j];
        bool ta = (a <= c);                             // half0 first = smaller index
        s += fmaxf((ta ? a : c) + qn, 0.f);
        i += ta; j += !ta;
    }
    s = waveReduceSum(s);
    if ((threadIdx.x & 63) == 0) atomicAdd(&acc[ACC_ALIGN], s);
}

// K3a: kNN-graph scan on Y_rigid (self-excluded), packed score+index partials.
__global__ __launch_bounds__(512, 8) void k_knn_scan(const float4* __restrict__ YrP,
                                                     float* __restrict__ pk) {
    __shared__ float md[NWAVE][QPB][6];
    int tid = threadIdx.x, wave = tid >> 6, lane = tid & 63;
    int b = blockIdx.y, qg = blockIdx.x, half = blockIdx.z;
    int q = qg * QPB + lane;
    const float4* cb = YrP + (size_t)b * NPAD;
    float4 qp = cb[q];

    float b0 = INFF, b1 = INFF, b2 = INFF, b3 = INFF, b4 = INFF;
    // all 64 queries of this block lie in candidate chunk ((half,qg>>2)&..)
    bool hasSelf = (half == (qg >> 5)) && (wave == ((qg >> 2) & 7));
    if (hasSelf)
        scanCH<true, true>(cb, half * 2048 + wave * CH, -2.f * qp.x, -2.f * qp.y,
                           -2.f * qp.z, q, b0, b1, b2, b3, b4);
    else
        scanCH<false, true>(cb, half * 2048 + wave * CH, -2.f * qp.x, -2.f * qp.y,
                            -2.f * qp.z, q, b0, b1, b2, b3, b4);

    md[wave][lane][0] = b0; md[wave][lane][1] = b1; md[wave][lane][2] = b2;
    md[wave][lane][3] = b3; md[wave][lane][4] = b4; md[wave][lane][5] = INFF;
    __syncthreads();

    if (tid < QPB) {
        int l = tid;
        int pp0 = 0, pp1 = 0, pp2 = 0, pp3 = 0, pp4 = 0, pp5 = 0, pp6 = 0, pp7 = 0;
        int qq = qg * QPB + l;
        float* dst = pk + (((size_t)b * NN + qq) * 2 + half) * 6;
#pragma unroll
        for (int k = 0; k < KK; ++k) {
            float best = INFF; int bw = 0;
            MERGE_STEP(0) MERGE_STEP(1) MERGE_STEP(2) MERGE_STEP(3)
            MERGE_STEP(4) MERGE_STEP(5) MERGE_STEP(6) MERGE_STEP(7)
            dst[k] = best;
            MERGE_ADV()
        }
        dst[5] = INFF;
    }
}

__device__ void finalize(const float* acc, float* out) {
    float a[ACC_COUNT];
#pragma unroll
    for (int i = 0; i < ACC_COUNT; ++i)
        a[i] = __hip_atomic_load(&acc[i], __ATOMIC_RELAXED, __HIP_MEMORY_SCOPE_AGENT);
    float L_rot = a[ACC_ROT] / BB;
    float L_trans = a[ACC_TRANS] / BB;
    float L_rmse = 0.f;
#pragma unroll
    for (int b = 0; b < BB; ++b) L_rmse += sqrtf(a[ACC_RMSE + b] / NN);
    L_rmse /= BB;
    float L_align = a[ACC_ALIGN] / ((float)BB * NN * KK);
    float L_disp = a[ACC_DISP] / ((float)BB * NN);
    float L_def = a[ACC_DEFORM] / ((float)BB * NN * KK);
    float L_lap = a[ACC_LAP] / ((float)BB * NN);
    float rigid = L_rot + L_trans + L_rmse;
    float nr = L_align + 0.01f * L_disp + 0.1f * L_def + 0.1f * L_lap;
    out[0] = rigid + nr; out[1] = rigid; out[2] = nr;
    out[3] = L_rot; out[4] = L_trans; out[5] = L_rmse;
    out[6] = L_align; out[7] = L_disp; out[8] = L_def; out[9] = L_lap;
}

// K3b: merge packed kNN partials, deform/lap epilogue, last-block finalize.
__global__ void m_knn(const float4* __restrict__ YrP, const float* __restrict__ Xh,
                      const float* __restrict__ dl, const float* __restrict__ pk,
                      float* __restrict__ acc, unsigned* __restrict__ doneCnt,
                      float* __restrict__ out) {
    int gid = blockIdx.x * MQ_BLK + threadIdx.x;       // 0 .. B*N-1
    int b = gid >> 12, q = gid & (NN - 1);
    const float4* cb = YrP + (size_t)b * NPAD;
    float4 qp = cb[q];

    const float* p0 = pk + (size_t)gid * 12;
    const float* p1 = p0 + 6;
    int i = 0, j = 0;
    int si[KK];
#pragma unroll
    for (int k = 0; k < KK; ++k) {
        float a = p0[i], c = p1[j];
        bool ta = (a <= c);
        si[k] = (int)(__float_as_uint(ta ? a : c) & 0xFFFu);
        i += ta; j += !ta;
    }

    const float* xh = Xh + (size_t)b * NN * 3;
    const float* dlb = dl + (size_t)b * NN * 3;
    float xnx = xh[q * 3 + 0], xny = xh[q * 3 + 1], xnz = xh[q * 3 + 2];
    float dnx = dlb[q * 3 + 0], dny = dlb[q * 3 + 1], dnz = dlb[q * 3 + 2];

    float def = 0.f, sx = 0.f, sy = 0.f, sz = 0.f;
#pragma unroll
    for (int k = 0; k < KK; ++k) {
        int n = si[k];
        float4 yj = cb[n];
        float ex = (xh[n * 3 + 0] - xnx) - (yj.x - qp.x);
        float ey = (xh[n * 3 + 1] - xny) - (yj.y - qp.y);
        float ez = (xh[n * 3 + 2] - xnz) - (yj.z - qp.z);
        def += ex * ex + ey * ey + ez * ez;
        sx += dlb[n * 3 + 0]; sy += dlb[n * 3 + 1]; sz += dlb[n * 3 + 2];
    }
    float lx = dnx - sx / 5.f, ly = dny - sy / 5.f, lz = dnz - sz / 5.f;
    float lap = lx * lx + ly * ly + lz * lz;

    def = waveReduceSum(def);
    lap = waveReduceSum(lap);
    if ((threadIdx.x & 63) == 0) {
        atomicAdd(&acc[ACC_DEFORM], def);
        atomicAdd(&acc[ACC_LAP], lap);
    }
    __syncthreads();
    if (threadIdx.x == 0) {
        __threadfence();
        unsigned t = __hip_atomic_fetch_add(doneCnt, 1u, __ATOMIC_ACQ_REL,
                                            __HIP_MEMORY_SCOPE_AGENT);
        if (t == M_KNN_BLOCKS - 1) finalize(acc, out);
    }
}

extern "C" void kernel_launch(void* const* d_in, const int* in_sizes, int n_in,
                              void* d_out, int out_size, void* d_ws, size_t ws_size,
                              hipStream_t stream) {
    const float* Y  = (const float*)d_in[0];
    const float* X  = (const float*)d_in[1];
    const float* Rp = (const float*)d_in[2];
    const float* tp = (const float*)d_in[3];
    const float* Rg = (const float*)d_in[4];
    const float* tg = (const float*)d_in[5];
    const float* Xh = (const float*)d_in[6];
    const float* dl = (const float*)d_in[7];
    float* out = (float*)d_out;

    float*    acc     = (float*)d_ws;                            // 14 floats
    unsigned* doneCnt = (unsigned*)((char*)d_ws + 64);
    float4*   YrP     = (float4*)((char*)d_ws + 512);            // 512 KB
    float4*   XP      = YrP + (size_t)BB * NPAD;                 // 512 KB
    float*    pa      = (float*)(XP + (size_t)BB * NPAD);        // B*N*2*6 = 1.5 MB
    float*    pk      = pa + (size_t)BB * NN * 12;               // 1.5 MB

    hipMemsetAsync(d_ws, 0, 512, stream);
    hipLaunchKernelGGL(k_prep, dim3(BB * NN / 256), dim3(256), 0, stream,
                       Y, X, Rp, tp, Rg, tg, dl, YrP, XP, acc);
    hipLaunchKernelGGL(k_align_scan, dim3(NN / QPB, BB, 2), dim3(512), 0, stream,
                       Xh, XP, pa);
    hipLaunchKernelGGL(m_align, dim3(BB * NN / MQ_BLK), dim3(MQ_BLK), 0, stream,
                       Xh, pa, acc);
    hipLaunchKernelGGL(k_knn_scan, dim3(NN / QPB, BB, 2), dim3(512), 0, stream,
                       YrP, pk);
    hipLaunchKernelGGL(m_knn, dim3(M_KNN_BLOCKS), dim3(MQ_BLK), 0, stream,
                       YrP, Xh, dl, pk, acc, doneCnt, out);
}